// Round 1
// baseline (1496.465 us; speedup 1.0000x reference)
//
#include <hip/hip_runtime.h>
#include <math.h>
#include <stdint.h>

// Bayesian DAG marginal propagation, N=4096 nodes, K=14 parents, C=2^14 configs.
//
// Strategy: persistent cooperative kernel, 256 blocks x 1024 threads (1 block/CU,
// all co-resident => spin-wait on parent flags is deadlock-free when block b
// processes nodes b, b+256, ... in increasing order).
//
// Per non-root node:
//   S = sum_c exp(log_prod[c]) * sigmoid(logit[c])
//   log_prod[c] = base + sum over set bits of diff[k]  (diff = plp - log1m)
//   -> collapsed into two 128-entry LDS tables (low/high 7 bits of c),
//      pre-multiplied by log2(e) so the inner loop is exp2(lo+hi)*rcp(1+exp2(-x*log2e)).
//   out[node] = S (== exp(logsumexp)), child payload lm = log(S).
//
// Flag doubles as payload: ws word = float bits of lm; sentinel 0x7F7F7F7F
// (memset 0x7F) == 3.39e38, unreachable since lm <= log(16384) ~ 9.7.

#define NN     4096
#define KK     14
#define CC     16384
#define NROOTS 64
#define NBLK   256
#define NTHR   1024
#define PT     (CC / NTHR)   // 16 elements per thread
#define SENTIN 0x7F7F7F7Fu

__global__ __launch_bounds__(NTHR, 4) void bayes_dag_kernel(
    const float* __restrict__ logits,
    const int*   __restrict__ parents,
    float*       __restrict__ out,
    unsigned*    __restrict__ lmflag)   // N words: float bits of log-marginal, SENTIN = not ready
{
    __shared__ float loS2[128];     // (loSum + base) * log2e
    __shared__ float hiS2[128];     // hiSum * log2e
    __shared__ float diffLds[KK];
    __shared__ float l1mLds[KK];
    __shared__ float redLds[NTHR / 64];

    const int tid  = threadIdx.x;
    const int lane = tid & 63;
    const int wv   = tid >> 6;

    const float LOG2E = 1.4426950408889634f;
    const float MINV  = -13.815510557964274f;     // log(1e-6)
    const float MAXV  = -1.0000005000001667e-06f; // log(1 - 1e-6)

    for (int node = blockIdx.x; node < NN; node += gridDim.x) {
        if (node < NROOTS) {
            // root: lm = log_sigmoid(logits[node][0]); out = exp(lm)
            if (tid == 0) {
                float x  = logits[(size_t)node * CC];
                float lm = fminf(x, 0.f) - log1pf(__expf(-fabsf(x)));
                out[node] = __expf(lm);
                __hip_atomic_store(&lmflag[node], __float_as_uint(lm),
                                   __ATOMIC_RELEASE, __HIP_MEMORY_SCOPE_AGENT);
            }
            continue;  // uniform per block: no barrier divergence
        }

        // ---- prefetch this node's 64KB logit row into registers (overlaps the spin) ----
        const float* row = logits + (size_t)node * CC;
        float xs[PT];
        #pragma unroll
        for (int m = 0; m < PT; ++m)
            xs[m] = row[m * NTHR + tid];

        // ---- wave 0: spin-wait for parents, compute per-parent diff / log1m ----
        if (wv == 0) {
            int p = 0;
            if (lane < KK) p = parents[node * KK + lane];
            unsigned v = SENTIN;
            int guard = 0;
            for (;;) {
                if (lane < KK)
                    v = __hip_atomic_load(&lmflag[p], __ATOMIC_ACQUIRE,
                                          __HIP_MEMORY_SCOPE_AGENT);
                bool rdy = (lane >= KK) || (v != SENTIN);
                if (__all(rdy)) break;
                if (++guard > (1 << 24)) break;   // visible-failure escape, never a hang
                __builtin_amdgcn_s_sleep(2);
            }
            if (lane < KK) {
                float plp = __uint_as_float(v);
                plp = fminf(fmaxf(plp, MINV), MAXV);
                float em  = fminf(__expf(plp), 1.f - 1e-6f);
                float l1m = log1pf(-em);
                diffLds[lane] = plp - l1m;
                l1mLds[lane]  = l1m;
            }
        }
        __syncthreads();

        // ---- build the two 7-bit tables ----
        // c bits MSB-first: bit b of (c&127) -> configs column k = 13-b,
        //                   bit b of (c>>7) -> configs column k = 6-b.
        if (tid < 128) {
            float base = 0.f;
            #pragma unroll
            for (int k = 0; k < KK; ++k) base += l1mLds[k];
            float s = base;
            #pragma unroll
            for (int b = 0; b < 7; ++b)
                if ((tid >> b) & 1) s += diffLds[13 - b];
            loS2[tid] = s * LOG2E;
        } else if (tid < 256) {
            int h = tid - 128;
            float s = 0.f;
            #pragma unroll
            for (int b = 0; b < 7; ++b)
                if ((h >> b) & 1) s += diffLds[6 - b];
            hiS2[h] = s * LOG2E;
        }
        __syncthreads();

        // ---- main accumulation: 16 elements per thread ----
        // c = m*1024 + tid: lo strides 1 across lanes (2-way bank alias: free),
        // hi is wave-uniform (broadcast).
        float acc = 0.f;
        #pragma unroll
        for (int m = 0; m < PT; ++m) {
            int   c = m * NTHR + tid;
            float x = xs[m];
            float p = exp2f(loS2[c & 127] + hiS2[c >> 7]);
            float e = exp2f(x * -LOG2E);
            acc += p * __builtin_amdgcn_rcpf(1.f + e);
        }

        // ---- reduce: wave shuffle, then cross-wave via LDS ----
        #pragma unroll
        for (int off = 32; off > 0; off >>= 1)
            acc += __shfl_down(acc, off, 64);
        if (lane == 0) redLds[wv] = acc;
        __syncthreads();
        if (tid == 0) {
            float S = 0.f;
            #pragma unroll
            for (int w = 0; w < NTHR / 64; ++w) S += redLds[w];
            out[node] = S;                 // == exp(logsumexp)
            float lm = __logf(S);          // S==0 -> -inf; children clip at log(1e-6)
            __hip_atomic_store(&lmflag[node], __float_as_uint(lm),
                               __ATOMIC_RELEASE, __HIP_MEMORY_SCOPE_AGENT);
        }
        // next iteration's __syncthreads orders LDS reuse; redLds read by tid0
        // precedes the next writes (which sit behind two barriers).
    }
}

extern "C" void kernel_launch(void* const* d_in, const int* in_sizes, int n_in,
                              void* d_out, int out_size, void* d_ws, size_t ws_size,
                              hipStream_t stream) {
    const float* logits  = (const float*)d_in[0];
    // d_in[1] = configs [C,K] — regenerated analytically, unused
    const int*   parents = (const int*)d_in[2];
    // d_in[3] = root_mask — node < 64, unused
    float*    out    = (float*)d_out;
    unsigned* lmflag = (unsigned*)d_ws;   // N words

    // sentinel-fill the flag/value array (0x7F7F7F7F = 3.39e38, unreachable lm)
    hipMemsetAsync(lmflag, 0x7F, NN * sizeof(unsigned), stream);

    void* args[] = { (void*)&logits, (void*)&parents, (void*)&out, (void*)&lmflag };
    hipLaunchCooperativeKernel((const void*)bayes_dag_kernel,
                               dim3(NBLK), dim3(NTHR), args, 0, stream);
}

// Round 2
// 613.371 us; speedup vs baseline: 2.4397x; 2.4397x over previous
//
#include <hip/hip_runtime.h>
#include <math.h>
#include <stdint.h>

// Bayesian DAG marginal propagation, N=4096, K=14 parents, C=2^14 configs.
//
// v2: linear-space bit-fold. S = sum_c sigma(x_c) * prod_k w_k factorizes over
// the 14 config bits, so after parents are ready we collapse the 16384-vector
// with 14 pairwise folds v' = fma(p, v1-v0, v0):
//   - 4 levels in-register (c bits 10..13 <-> parents 3..0)
//   - 6 levels via shfl_xor   (c bits 0..5  <-> parents 13..8)
//   - 4 levels cross-wave LDS (c bits 6..9  <-> parents 7..4)
// sigma(x_c) is parent-INDEPENDENT and is computed before the spin; the next
// node's 64KB row is prefetched before the spin. Post-dependency critical work
// is ~30 FMAs + 6 shuffles instead of 16384 exponentials.
//
// Flag word IS the payload (parent marginal probability S; children clip to
// [1e-6, 1-1e-6] which reproduces the reference's log-space clip chain
// exactly). Sentinel 0x7F7F7F7F = 3.39e38 unreachable (S <= 16384).
// Relaxed agent-scope atomics suffice: no separate data to order.

#define NN     4096
#define KK     14
#define CC     16384
#define NROOTS 64
#define NBLK   256
#define NTHR   1024
#define PT     (CC / NTHR)   // 16 elements per thread
#define SENTIN 0x7F7F7F7Fu

__global__ __launch_bounds__(NTHR, 4) void bayes_dag_kernel(
    const float* __restrict__ logits,
    const int*   __restrict__ parents,
    float*       __restrict__ out,
    unsigned*    __restrict__ flagv)   // N words: float bits of marginal prob
{
    __shared__ float pvals[KK];        // clipped parent probabilities
    __shared__ float redLds[NTHR / 64];

    const int tid  = threadIdx.x;
    const int lane = tid & 63;
    const int wv   = tid >> 6;
    const float LOG2E = 1.4426950408889634f;

    int node = blockIdx.x;
    if (node < NROOTS) {
        // root: marginal = sigmoid(logits[node][0])
        if (tid == 0) {
            float x = logits[(size_t)node * CC];
            float p = __builtin_amdgcn_rcpf(1.f + exp2f(-x * LOG2E));
            out[node] = p;
            __hip_atomic_store(&flagv[node], __float_as_uint(p),
                               __ATOMIC_RELAXED, __HIP_MEMORY_SCOPE_AGENT);
        }
        node += NBLK;
    }

    // preload first row: c = m*NTHR + tid (fully coalesced dwords)
    float xs[PT];
    {
        const float* row = logits + (size_t)node * CC;
        #pragma unroll
        for (int m = 0; m < PT; ++m) xs[m] = row[m * NTHR + tid];
    }

    for (; node < NN; node += NBLK) {
        // ---- issue prefetch of the next node's row (in flight during spin) ----
        const int   nxt  = node + NBLK;
        const float* nrow = logits + (size_t)(nxt < NN ? nxt : node) * CC;
        float xn[PT];
        #pragma unroll
        for (int m = 0; m < PT; ++m) xn[m] = nrow[m * NTHR + tid];

        // ---- parent-independent work: sigmoid of current row ----
        float sig[PT];
        #pragma unroll
        for (int m = 0; m < PT; ++m)
            sig[m] = __builtin_amdgcn_rcpf(1.f + exp2f(-xs[m] * LOG2E));

        // ---- wave 0: spin on parent flags, publish clipped probabilities ----
        if (wv == 0) {
            int p = 0;
            if (lane < KK) p = parents[node * KK + lane];
            unsigned v = SENTIN;
            int guard = 0;
            for (;;) {
                if (lane < KK)
                    v = __hip_atomic_load(&flagv[p], __ATOMIC_RELAXED,
                                          __HIP_MEMORY_SCOPE_AGENT);
                if (__all(lane >= KK || v != SENTIN)) break;
                if (++guard > (1 << 22)) break;   // visible-failure escape
                __builtin_amdgcn_s_sleep(1);
            }
            if (lane < KK) {
                float pf = __uint_as_float(v);
                pvals[lane] = fminf(fmaxf(pf, 1e-6f), 1.f - 1e-6f);
            }
        }
        __syncthreads();

        // broadcast parent probs to registers
        float pv[KK];
        #pragma unroll
        for (int k = 0; k < KK; ++k) pv[k] = pvals[k];

        // ---- 4 in-register fold levels: m bit j <-> c bit 10+j <-> parent 3-j ----
        float v8[8];
        #pragma unroll
        for (int j = 0; j < 8; ++j)
            v8[j] = fmaf(pv[3], sig[2*j+1] - sig[2*j], sig[2*j]);
        float v4[4];
        #pragma unroll
        for (int j = 0; j < 4; ++j)
            v4[j] = fmaf(pv[2], v8[2*j+1] - v8[2*j], v8[2*j]);
        float v2[2];
        #pragma unroll
        for (int j = 0; j < 2; ++j)
            v2[j] = fmaf(pv[1], v4[2*j+1] - v4[2*j], v4[2*j]);
        float acc = fmaf(pv[0], v2[1] - v2[0], v2[0]);

        // ---- 6 lane fold levels: lane bit t <-> c bit t <-> parent 13-t ----
        #pragma unroll
        for (int t = 0; t < 6; ++t) {
            float other = __shfl_xor(acc, 1 << t, 64);
            bool  bit   = (lane >> t) & 1;
            float a = bit ? other : acc;   // value with this config bit = 0
            float b = bit ? acc : other;   // value with this config bit = 1
            acc = fmaf(pv[13 - t], b - a, a);
        }
        if (lane == 0) redLds[wv] = acc;
        __syncthreads();

        // ---- 4 cross-wave fold levels: wv bit t <-> c bit 6+t <-> parent 7-t ----
        if (wv == 0) {
            float val = (lane < NTHR / 64) ? redLds[lane] : 0.f;
            #pragma unroll
            for (int t = 0; t < 4; ++t) {
                float other = __shfl_xor(val, 1 << t, 64);
                bool  bit   = (lane >> t) & 1;
                float a = bit ? other : val;
                float b = bit ? val : other;
                val = fmaf(pv[7 - t], b - a, a);
            }
            if (lane == 0) {
                out[node] = val;           // == exp(logsumexp(...))
                __hip_atomic_store(&flagv[node], __float_as_uint(val),
                                   __ATOMIC_RELAXED, __HIP_MEMORY_SCOPE_AGENT);
            }
        }

        // rotate prefetch buffer (compiler places the vmcnt wait here; by the
        // next use the load has had a full node interval to land)
        #pragma unroll
        for (int m = 0; m < PT; ++m) xs[m] = xn[m];
    }
}

extern "C" void kernel_launch(void* const* d_in, const int* in_sizes, int n_in,
                              void* d_out, int out_size, void* d_ws, size_t ws_size,
                              hipStream_t stream) {
    const float* logits  = (const float*)d_in[0];
    // d_in[1] = configs — encoded analytically in the fold order, unused
    const int*   parents = (const int*)d_in[2];
    // d_in[3] = root_mask — node < 64, unused
    float*    out   = (float*)d_out;
    unsigned* flagv = (unsigned*)d_ws;   // N words

    hipMemsetAsync(flagv, 0x7F, NN * sizeof(unsigned), stream);

    void* args[] = { (void*)&logits, (void*)&parents, (void*)&out, (void*)&flagv };
    hipLaunchCooperativeKernel((const void*)bayes_dag_kernel,
                               dim3(NBLK), dim3(NTHR), args, 0, stream);
}